// Round 14
// baseline (645.351 us; speedup 1.0000x reference)
//
#include <hip/hip_runtime.h>
#include <cmath>

// GATv2 3-layer forward, round 13:
//  - hc layers now SPLIT like layer 2 (R3's 2x win): edge-parallel k_logit_hc
//    (lane = (edge, head), no shuffles) + lean aggregation (per-head max
//    pre-pass, exp2 + weighted gather only). Removes logit math + online
//    softmax from the serial gather loop.
//  - logits stored [slot][8] f32 (27 MB), aliased with layer-2 logit buffer.
//  - GEMMs / CSR / prep / node_l2 byte-identical to R13 (361.2 us baseline).

#define NFEAT 128
#define HID 256
#define NCLS 47
#define L2PAD 64
#define LOG2E 1.44269504088896340736f

typedef __attribute__((ext_vector_type(8))) short bf16x8;
typedef __attribute__((ext_vector_type(4))) float f32x4;
typedef __attribute__((ext_vector_type(2))) float f32x2;

__device__ __forceinline__ unsigned short f2b(float f) {
  unsigned int u = __builtin_bit_cast(unsigned int, f);
  u += 0x7FFFu + ((u >> 16) & 1u);  // RNE
  return (unsigned short)(u >> 16);
}
__device__ __forceinline__ float b2f(unsigned short s) {
  return __builtin_bit_cast(float, (unsigned int)s << 16);
}
__device__ __forceinline__ f32x2 b2f2(unsigned int u) {
  return (f32x2){__builtin_bit_cast(float, u << 16),
                 __builtin_bit_cast(float, u & 0xFFFF0000u)};
}
__device__ __forceinline__ void glds16(const unsigned short* g, unsigned short* l) {
  __builtin_amdgcn_global_load_lds(
      (const __attribute__((address_space(1))) unsigned int*)g,
      (__attribute__((address_space(3))) unsigned int*)l, 16, 0, 0);
}
__device__ __forceinline__ float quad_max(float v) {
  int t = __builtin_amdgcn_mov_dpp(__builtin_bit_cast(int, v), 0xB1, 0xF, 0xF, true);
  v = fmaxf(v, __builtin_bit_cast(float, t));
  t = __builtin_amdgcn_mov_dpp(__builtin_bit_cast(int, v), 0x4E, 0xF, 0xF, true);
  v = fmaxf(v, __builtin_bit_cast(float, t));
  return v;
}

// ---------------- kernel 1: weight transposes + att pad + deg init ----------------
struct WtArgs {
  const float* W[6];
  unsigned short* WT[6];
  int K[6], M[6], off[6], total;
  const float* att;
  float* att48;
  int* deg;
  int n;
};
__global__ void k_wt_all(WtArgs a) {
  int i = blockIdx.x * blockDim.x + threadIdx.x;
  if (i >= a.total) {
    int j = i - a.total;
    if (j < 48) { a.att48[j] = (j < NCLS) ? a.att[j] * LOG2E : 0.f; return; }
    j -= 48;
    if (j < a.n) a.deg[j] = 1;
    return;
  }
  int s = 0;
  #pragma unroll
  for (int j = 1; j < 6; ++j) if (i >= a.off[j]) s = j;
  int jj = i - a.off[s];
  int K = a.K[s], M = a.M[s];
  int m = jj / K, k = jj - m * K;
  a.WT[s][jj] = (m < M) ? f2b(a.W[s][(size_t)k * M + m]) : (unsigned short)0;
}

// ---------------- kernel 2: cast x to bf16 + degree count ----------------
__global__ void k_cast_count(const float* __restrict__ in,
                             unsigned short* __restrict__ out, int n4,
                             const int* __restrict__ dst,
                             int* __restrict__ deg, int e) {
  int i = blockIdx.x * blockDim.x + threadIdx.x;
  if (i < n4) {
    float4 v = reinterpret_cast<const float4*>(in)[i];
    ushort4 o = {f2b(v.x), f2b(v.y), f2b(v.z), f2b(v.w)};
    reinterpret_cast<ushort4*>(out)[i] = o;
  } else {
    int j = i - n4;
    if (j < e) atomicAdd(&deg[dst[j]], 1);
  }
}

// ---------------- CSR build ----------------
__global__ __launch_bounds__(256) void k_bsum(const int* __restrict__ deg,
                                              int* __restrict__ bsum, int n) {
  int t = threadIdx.x;
  int base = blockIdx.x * 1024 + t * 4;
  int s = 0;
  if (base + 3 < n) {
    int4 v = *reinterpret_cast<const int4*>(deg + base);
    s = v.x + v.y + v.z + v.w;
  } else {
    for (int j = 0; j < 4; ++j) { int i = base + j; if (i < n) s += deg[i]; }
  }
  #pragma unroll
  for (int off = 1; off < 64; off <<= 1) s += __shfl_xor(s, off, 64);
  __shared__ int wsum[4];
  if ((t & 63) == 0) wsum[t >> 6] = s;
  __syncthreads();
  if (t == 0) bsum[blockIdx.x] = wsum[0] + wsum[1] + wsum[2] + wsum[3];
}

__global__ void k_scanb(int* __restrict__ bsum, int nb) {
  int lane = threadIdx.x;
  int v = (lane < nb) ? bsum[lane] : 0;
  #pragma unroll
  for (int off = 1; off < 64; off <<= 1) {
    int u = __shfl_up(v, off, 64);
    if (lane >= off) v += u;
  }
  if (lane < nb) bsum[lane] = v;
}

__global__ __launch_bounds__(256) void k_scanfinal(const int* __restrict__ deg,
                                                   const int* __restrict__ bscan,
                                                   int* __restrict__ rowptr,
                                                   int2* __restrict__ csr,
                                                   int* __restrict__ cursor, int n) {
  int t = threadIdx.x, b = blockIdx.x;
  int base = b * 1024 + t * 4;
  int v0 = 0, v1 = 0, v2 = 0, v3 = 0;
  if (base + 3 < n) {
    int4 v = *reinterpret_cast<const int4*>(deg + base);
    v0 = v.x; v1 = v.y; v2 = v.z; v3 = v.w;
  } else {
    if (base < n) v0 = deg[base];
    if (base + 1 < n) v1 = deg[base + 1];
    if (base + 2 < n) v2 = deg[base + 2];
    if (base + 3 < n) v3 = deg[base + 3];
  }
  int s = v0 + v1 + v2 + v3;
  int incl = s;
  #pragma unroll
  for (int off = 1; off < 64; off <<= 1) {
    int u = __shfl_up(incl, off, 64);
    if ((t & 63) >= off) incl += u;
  }
  __shared__ int wsum[4];
  int w = t >> 6, l = t & 63;
  if (l == 63) wsum[w] = incl;
  __syncthreads();
  int woff = 0;
  for (int j = 0; j < w; ++j) woff += wsum[j];
  int excl = incl - s + woff;
  int boff = (b == 0) ? 0 : bscan[b - 1];
  int p0 = boff + excl;
  int p1 = p0 + v0, p2 = p1 + v1, p3 = p2 + v2, p4 = p3 + v3;
  if (base < n)     { rowptr[base + 1] = p1; csr[p0] = make_int2(base, base);         cursor[base]     = p0 + 1; }
  if (base + 1 < n) { rowptr[base + 2] = p2; csr[p1] = make_int2(base + 1, base + 1); cursor[base + 1] = p1 + 1; }
  if (base + 2 < n) { rowptr[base + 3] = p3; csr[p2] = make_int2(base + 2, base + 2); cursor[base + 2] = p2 + 1; }
  if (base + 3 < n) { rowptr[base + 4] = p4; csr[p3] = make_int2(base + 3, base + 3); cursor[base + 3] = p3 + 1; }
  if (b == 0 && t == 0) rowptr[0] = 0;
}

__global__ void k_scatter(const int* __restrict__ src, const int* __restrict__ dst,
                          int* __restrict__ cursor, int2* __restrict__ csr, int e) {
  int i = blockIdx.x * blockDim.x + threadIdx.x;
  if (i < e) {
    int d = dst[i];
    int p = atomicAdd(&cursor[d], 1);
    csr[p] = make_int2(src[i], d);
  }
}

// ---------------- 128x128 dual bf16 MFMA GEMM ----------------
__global__ __launch_bounds__(512) void gemm_dual_bf16_128(
    const unsigned short* __restrict__ X, const unsigned short* __restrict__ WlT,
    const unsigned short* __restrict__ WrT, unsigned short* __restrict__ XL,
    unsigned short* __restrict__ XR, int N, int K, int Mpad) {
  __shared__ __align__(16) unsigned short S[3 * 128 * 64];
  unsigned short* Xs = S;
  unsigned short* Ls = S + 8192;
  unsigned short* Rs = S + 16384;

  const int t = threadIdx.x;
  const int col0 = blockIdx.x * 128;
  const int row0 = blockIdx.y * 128;
  const int w = t >> 6, lane = t & 63;
  const int wr = w >> 2, wc = w & 3;
  const int r15 = lane & 15, kc = lane >> 4;
  const bool tail = (row0 + 128 > N);

  const int row_a = t >> 3,          c16_a = t & 7;
  const int row_b = (t + 512) >> 3,  c16_b = t & 7;
  const int sg_a = (c16_a ^ (row_a & 7)) * 8;
  const int sg_b = (c16_b ^ (row_b & 7)) * 8;
  unsigned short* d0 = S + w * 512;
  unsigned short* d1 = S + 4096 + w * 512;

  f32x4 accL[4][2], accR[4][2];
  #pragma unroll
  for (int rf = 0; rf < 4; ++rf)
    #pragma unroll
    for (int cf = 0; cf < 2; ++cf) {
      accL[rf][cf] = (f32x4){0.f, 0.f, 0.f, 0.f};
      accR[rf][cf] = (f32x4){0.f, 0.f, 0.f, 0.f};
    }

  for (int k0 = 0; k0 < K; k0 += 64) {
    glds16(WlT + (size_t)(col0 + row_a) * K + k0 + sg_a, d0 + 8192);
    glds16(WlT + (size_t)(col0 + row_b) * K + k0 + sg_b, d1 + 8192);
    glds16(WrT + (size_t)(col0 + row_a) * K + k0 + sg_a, d0 + 16384);
    glds16(WrT + (size_t)(col0 + row_b) * K + k0 + sg_b, d1 + 16384);
    if (!tail) {
      glds16(X + (size_t)(row0 + row_a) * K + k0 + sg_a, d0);
      glds16(X + (size_t)(row0 + row_b) * K + k0 + sg_b, d1);
    } else {
      uint4 va = (uint4){0, 0, 0, 0}, vb = (uint4){0, 0, 0, 0};
      if (row0 + row_a < N)
        va = *reinterpret_cast<const uint4*>(X + (size_t)(row0 + row_a) * K + k0 + sg_a);
      if (row0 + row_b < N)
        vb = *reinterpret_cast<const uint4*>(X + (size_t)(row0 + row_b) * K + k0 + sg_b);
      *reinterpret_cast<uint4*>(Xs + row_a * 64 + c16_a * 8) = va;
      *reinterpret_cast<uint4*>(Xs + row_b * 64 + c16_b * 8) = vb;
    }
    __syncthreads();

    #pragma unroll
    for (int ks = 0; ks < 2; ++ks) {
      const int c16 = ks * 4 + kc;
      bf16x8 a[4];
      #pragma unroll
      for (int rf = 0; rf < 4; ++rf) {
        const int rA = wr * 64 + rf * 16 + r15;
        a[rf] = *reinterpret_cast<const bf16x8*>(Xs + rA * 64 + ((c16 ^ (rA & 7)) * 8));
      }
      #pragma unroll
      for (int cf = 0; cf < 2; ++cf) {
        const int rB = wc * 32 + cf * 16 + r15;
        const int so = rB * 64 + ((c16 ^ (rB & 7)) * 8);
        const bf16x8 bl = *reinterpret_cast<const bf16x8*>(Ls + so);
        const bf16x8 br = *reinterpret_cast<const bf16x8*>(Rs + so);
        #pragma unroll
        for (int rf = 0; rf < 4; ++rf) {
          accL[rf][cf] = __builtin_amdgcn_mfma_f32_16x16x32_bf16(a[rf], bl, accL[rf][cf], 0, 0, 0);
          accR[rf][cf] = __builtin_amdgcn_mfma_f32_16x16x32_bf16(a[rf], br, accR[rf][cf], 0, 0, 0);
        }
      }
    }
    __syncthreads();
  }

  #pragma unroll
  for (int rf = 0; rf < 4; ++rf) {
    #pragma unroll
    for (int cf = 0; cf < 2; ++cf) {
      int cc = col0 + wc * 32 + cf * 16 + r15;
      #pragma unroll
      for (int i = 0; i < 4; ++i) {
        int rr = row0 + wr * 64 + rf * 16 + kc * 4 + i;
        if (rr < N) {
          XL[(size_t)rr * Mpad + cc] = f2b(accL[rf][cf][i]);
          XR[(size_t)rr * Mpad + cc] = f2b(accR[rf][cf][i]);
        }
      }
    }
  }
}

// ---------------- 64x64 dual GEMM (layer 2) ----------------
__global__ __launch_bounds__(256) void gemm_dual_bf16(
    const unsigned short* __restrict__ X, const unsigned short* __restrict__ WlT,
    const unsigned short* __restrict__ WrT, unsigned short* __restrict__ XL,
    unsigned short* __restrict__ XR, int N, int K, int Mpad) {
  __shared__ __align__(16) unsigned short S[3 * 64 * 64];
  unsigned short* Xs = S;
  unsigned short* Ls = S + 4096;
  unsigned short* Rs = S + 8192;

  const int t = threadIdx.x;
  const int col0 = blockIdx.x * 64;
  const int row0 = blockIdx.y * 64;
  const int w = t >> 6, lane = t & 63;
  const int r15 = lane & 15, kc = lane >> 4;
  const bool tail = (row0 + 64 > N);

  const int rowa = t >> 3, c16a = t & 7;
  const int rowb = (t + 256) >> 3, c16b = t & 7;
  const int sga = (c16a ^ (rowa & 7)) * 8;
  const int sgb = (c16b ^ (rowb & 7)) * 8;
  unsigned short* ldst0 = S + (w * 512);
  unsigned short* ldst1 = S + (2048 + w * 512);

  f32x4 accL[4], accR[4];
  #pragma unroll
  for (int i = 0; i < 4; ++i) {
    accL[i] = (f32x4){0.f, 0.f, 0.f, 0.f};
    accR[i] = (f32x4){0.f, 0.f, 0.f, 0.f};
  }

  const int rA = 16 * w + r15;

  for (int k0 = 0; k0 < K; k0 += 64) {
    glds16(WlT + (size_t)(col0 + rowa) * K + k0 + sga, ldst0 + 4096);
    glds16(WlT + (size_t)(col0 + rowb) * K + k0 + sgb, ldst1 + 4096);
    glds16(WrT + (size_t)(col0 + rowa) * K + k0 + sga, ldst0 + 8192);
    glds16(WrT + (size_t)(col0 + rowb) * K + k0 + sgb, ldst1 + 8192);
    if (!tail) {
      glds16(X + (size_t)(row0 + rowa) * K + k0 + sga, ldst0);
      glds16(X + (size_t)(row0 + rowb) * K + k0 + sgb, ldst1);
    } else {
      uint4 va = (uint4){0, 0, 0, 0}, vb = (uint4){0, 0, 0, 0};
      if (row0 + rowa < N)
        va = *reinterpret_cast<const uint4*>(X + (size_t)(row0 + rowa) * K + k0 + sga);
      if (row0 + rowb < N)
        vb = *reinterpret_cast<const uint4*>(X + (size_t)(row0 + rowb) * K + k0 + sgb);
      *reinterpret_cast<uint4*>(Xs + rowa * 64 + c16a * 8) = va;
      *reinterpret_cast<uint4*>(Xs + rowb * 64 + c16b * 8) = vb;
    }
    __syncthreads();

    #pragma unroll
    for (int ks = 0; ks < 2; ++ks) {
      const int c16 = ks * 4 + kc;
      const bf16x8 a = *reinterpret_cast<const bf16x8*>(
          Xs + rA * 64 + ((c16 ^ (rA & 7)) * 8));
      #pragma unroll
      for (int nf = 0; nf < 4; ++nf) {
        const int rB = nf * 16 + r15;
        const int so = rB * 64 + ((c16 ^ (rB & 7)) * 8);
        const bf16x8 bl = *reinterpret_cast<const bf16x8*>(Ls + so);
        const bf16x8 br = *reinterpret_cast<const bf16x8*>(Rs + so);
        accL[nf] = __builtin_amdgcn_mfma_f32_16x16x32_bf16(a, bl, accL[nf], 0, 0, 0);
        accR[nf] = __builtin_amdgcn_mfma_f32_16x16x32_bf16(a, br, accR[nf], 0, 0, 0);
      }
    }
    __syncthreads();
  }

  #pragma unroll
  for (int nf = 0; nf < 4; ++nf) {
    int cc = col0 + nf * 16 + r15;
    #pragma unroll
    for (int i = 0; i < 4; ++i) {
      int rr = row0 + 16 * w + kc * 4 + i;
      if (rr < N) {
        XL[(size_t)rr * Mpad + cc] = f2b(accL[nf][i]);
        XR[(size_t)rr * Mpad + cc] = f2b(accR[nf][i]);
      }
    }
  }
}

// ---------------- hc edge logits: lane = (CSR slot, head) ----------------
// logit8[8*slot + h] = LOG2E * sum_c lrelu(xl[src][32h+c] + xr[dst][32h+c]) * att[h][c]
__global__ __launch_bounds__(256) void k_logit_hc(
    const unsigned short* __restrict__ xl, const unsigned short* __restrict__ xr,
    const float* __restrict__ att, const int2* __restrict__ csr,
    float* __restrict__ logit8, int total) {
  int idx = blockIdx.x * blockDim.x + threadIdx.x;
  int e = idx >> 3, h = idx & 7;
  if (e >= total) return;
  const int2 ed = csr[e];
  const uint4* pl = reinterpret_cast<const uint4*>(xl + (size_t)ed.x * HID + h * 32);
  const uint4* pr = reinterpret_cast<const uint4*>(xr + (size_t)ed.y * HID + h * 32);
  const f32x2* a2 = reinterpret_cast<const f32x2*>(att + h * 32);
  f32x2 s2 = {0.f, 0.f};
  #pragma unroll
  for (int b = 0; b < 4; ++b) {
    const uint4 xu = pl[b], xv = pr[b];
    const unsigned ua[4] = {xu.x, xu.y, xu.z, xu.w};
    const unsigned va[4] = {xv.x, xv.y, xv.z, xv.w};
    #pragma unroll
    for (int j = 0; j < 4; ++j) {
      f32x2 z = b2f2(ua[j]) + b2f2(va[j]);
      f32x2 lz = 0.2f * z;
      f32x2 r = {fmaxf(z.x, lz.x), fmaxf(z.y, lz.y)};
      s2 += r * a2[b * 4 + j];
    }
  }
  logit8[idx] = (s2.x + s2.y) * LOG2E;  // log2 units
}

// ---------------- hc aggregation (layers 0/1) ----------------
// 1 wave/node; half-wave per edge, 2 edges/iter; slot q holds values
// [8q,8q+8); head = q>>2. Logits precomputed; per-head max pre-pass; exp2.
__global__ __launch_bounds__(256) void gat_node_hc(
    const unsigned short* __restrict__ xl, const float* __restrict__ logit8,
    const float* __restrict__ bias, const int* __restrict__ rowptr,
    const int2* __restrict__ csr, unsigned short* __restrict__ out, int n) {
  int wid = (blockIdx.x * blockDim.x + threadIdx.x) >> 6;
  int lane = threadIdx.x & 63;
  if (wid >= n) return;
  const int q = lane & 31, half = lane >> 5;
  const int h = q >> 2;

  const int beg = rowptr[wid], end = rowptr[wid + 1];
  const int* csr_src = reinterpret_cast<const int*>(csr);

  // per-(node,head) max: quad lanes stride the edge list, DPP quad-max.
  // Both halves compute identical mx (same q) -> no cross-half max merge.
  float mx = -1e30f;
  for (int i = beg + (q & 3); i < end; i += 4)
    mx = fmaxf(mx, logit8[8 * i + h]);
  mx = quad_max(mx);

  float denom = 0.f;
  f32x2 acc[4] = {{0.f, 0.f}, {0.f, 0.f}, {0.f, 0.f}, {0.f, 0.f}};

  for (int base = beg; base < end; base += 2) {
    const int i = base + half;
    const bool act = i < end;
    const int ii = act ? i : base;
    const int u = csr_src[2 * ii];
    const uint4 p = *reinterpret_cast<const uint4*>(xl + (size_t)u * HID + q * 8);
    float w = exp2f(logit8[8 * ii + h] - mx);
    if (!act) w = 0.f;
    denom += w;
    acc[0] += w * b2f2(p.x);
    acc[1] += w * b2f2(p.y);
    acc[2] += w * b2f2(p.z);
    acc[3] += w * b2f2(p.w);
  }

  // merge halves (same mx -> plain add)
  denom += __shfl_xor(denom, 32, 64);
  #pragma unroll
  for (int j = 0; j < 4; ++j) {
    acc[j].x += __shfl_xor(acc[j].x, 32, 64);
    acc[j].y += __shfl_xor(acc[j].y, 32, 64);
  }

  if (half == 0) {
    const float inv = 1.f / (denom + 1e-16f);
    const float4 bf0 = *reinterpret_cast<const float4*>(bias + q * 8);
    const float4 bf1 = *reinterpret_cast<const float4*>(bias + q * 8 + 4);
    float o[8] = {acc[0].x * inv + bf0.x, acc[0].y * inv + bf0.y,
                  acc[1].x * inv + bf0.z, acc[1].y * inv + bf0.w,
                  acc[2].x * inv + bf1.x, acc[2].y * inv + bf1.y,
                  acc[3].x * inv + bf1.z, acc[3].y * inv + bf1.w};
    #pragma unroll
    for (int j = 0; j < 8; ++j) o[j] = o[j] > 0.f ? o[j] : (__expf(o[j]) - 1.f);
    uint4 ov;
    ov.x = (unsigned)f2b(o[0]) | ((unsigned)f2b(o[1]) << 16);
    ov.y = (unsigned)f2b(o[2]) | ((unsigned)f2b(o[3]) << 16);
    ov.z = (unsigned)f2b(o[4]) | ((unsigned)f2b(o[5]) << 16);
    ov.w = (unsigned)f2b(o[6]) | ((unsigned)f2b(o[7]) << 16);
    *reinterpret_cast<uint4*>(out + (size_t)wid * HID + q * 8) = ov;
  }
}

// ---------------- layer-2 edge logits (lane = CSR slot) ----------------
__global__ __launch_bounds__(256) void k_logit_l2(
    const unsigned short* __restrict__ xl, const unsigned short* __restrict__ xr,
    const float* __restrict__ att48, const int2* __restrict__ csr,
    float* __restrict__ logit, int total) {
  int i = blockIdx.x * blockDim.x + threadIdx.x;
  if (i >= total) return;
  const int2 e = csr[i];
  const uint4* pu = reinterpret_cast<const uint4*>(xl + (size_t)e.x * L2PAD);
  const uint4* pv = reinterpret_cast<const uint4*>(xr + (size_t)e.y * L2PAD);
  f32x2 s2 = {0.f, 0.f};
  #pragma unroll
  for (int b = 0; b < 6; ++b) {
    const uint4 xu = pu[b], xv = pv[b];
    const f32x2* a2 = reinterpret_cast<const f32x2*>(att48 + b * 8);
    const unsigned ua[4] = {xu.x, xu.y, xu.z, xu.w};
    const unsigned va[4] = {xv.x, xv.y, xv.z, xv.w};
    #pragma unroll
    for (int j = 0; j < 4; ++j) {
      f32x2 z = b2f2(ua[j]) + b2f2(va[j]);
      f32x2 lz = 0.2f * z;
      f32x2 r = {fmaxf(z.x, lz.x), fmaxf(z.y, lz.y)};
      s2 += r * a2[j];
    }
  }
  logit[i] = s2.x + s2.y;  // log2 units (att48 pre-scaled)
}

// ---------------- layer-2 aggregation + log_softmax ----------------
// QUARTER-WAVE per node: lane q in [0,16) holds classes {4q..4q+3}.
__global__ __launch_bounds__(256) void gat_node_l2(
    const unsigned short* __restrict__ xl, const float* __restrict__ logit,
    const float* __restrict__ bias, const int* __restrict__ rowptr,
    const int2* __restrict__ csr, float* __restrict__ out, int n) {
  int tid = blockIdx.x * blockDim.x + threadIdx.x;
  int node = tid >> 4;
  int q = threadIdx.x & 15;
  if (node >= n) return;
  const int c0 = 4 * q;
  const bool g0 = c0 < NCLS;
  const bool a1 = (c0 + 1) < NCLS, a2c = (c0 + 2) < NCLS, a3 = (c0 + 3) < NCLS;
  const int beg = rowptr[node], end = rowptr[node + 1];
  const int* csr_src = reinterpret_cast<const int*>(csr);

  float mx = -1e30f;
  for (int i = beg + q; i < end; i += 16) mx = fmaxf(mx, logit[i]);
  #pragma unroll
  for (int off = 1; off < 16; off <<= 1) mx = fmaxf(mx, __shfl_xor(mx, off, 64));

  float denom = 0.f;
  f32x2 acc0 = {0.f, 0.f}, acc1 = {0.f, 0.f};
  int i = beg;
  for (; i + 1 < end; i += 2) {
    const int u0 = csr_src[2 * i], u1 = csr_src[2 * (i + 1)];
    uint2 p0 = {0u, 0u}, p1 = {0u, 0u};
    if (g0) {
      p0 = *reinterpret_cast<const uint2*>(xl + (size_t)u0 * L2PAD + c0);
      p1 = *reinterpret_cast<const uint2*>(xl + (size_t)u1 * L2PAD + c0);
    }
    const float w0 = exp2f(logit[i] - mx);
    const float w1 = exp2f(logit[i + 1] - mx);
    denom += w0 + w1;
    acc0 += w0 * b2f2(p0.x) + w1 * b2f2(p1.x);
    acc1 += w0 * b2f2(p0.y) + w1 * b2f2(p1.y);
  }
  if (i < end) {
    const int u0 = csr_src[2 * i];
    uint2 p0 = {0u, 0u};
    if (g0) p0 = *reinterpret_cast<const uint2*>(xl + (size_t)u0 * L2PAD + c0);
    const float w0 = exp2f(logit[i] - mx);
    denom += w0;
    acc0 += w0 * b2f2(p0.x);
    acc1 += w0 * b2f2(p0.y);
  }

  const float inv = 1.f / (denom + 1e-16f);
  f32x2 r0 = acc0 * inv, r1 = acc1 * inv;
  if (g0)  r0.x += bias[c0];
  if (a1)  r0.y += bias[c0 + 1];
  if (a2c) r1.x += bias[c0 + 2];
  if (a3)  r1.y += bias[c0 + 3];

  float rm = -1e30f;
  if (g0)  rm = fmaxf(rm, r0.x);
  if (a1)  rm = fmaxf(rm, r0.y);
  if (a2c) rm = fmaxf(rm, r1.x);
  if (a3)  rm = fmaxf(rm, r1.y);
  #pragma unroll
  for (int off = 1; off < 16; off <<= 1) rm = fmaxf(rm, __shfl_xor(rm, off, 64));
  float se = 0.f;
  if (g0)  se += __expf(r0.x - rm);
  if (a1)  se += __expf(r0.y - rm);
  if (a2c) se += __expf(r1.x - rm);
  if (a3)  se += __expf(r1.y - rm);
  #pragma unroll
  for (int off = 1; off < 16; off <<= 1) se += __shfl_xor(se, off, 64);
  const float ls = rm + __logf(se);
  float* o = out + (size_t)node * NCLS;
  if (g0)  o[c0] = r0.x - ls;
  if (a1)  o[c0 + 1] = r0.y - ls;
  if (a2c) o[c0 + 2] = r1.x - ls;
  if (a3)  o[c0 + 3] = r1.y - ls;
}

// ---------------- launch ----------------
extern "C" void kernel_launch(void* const* d_in, const int* in_sizes, int n_in,
                              void* d_out, int out_size, void* d_ws, size_t ws_size,
                              hipStream_t stream) {
  const float* x   = (const float*)d_in[0];
  const int* ei    = (const int*)d_in[1];
  const float* Wl0 = (const float*)d_in[2];
  const float* Wr0 = (const float*)d_in[3];
  const float* a0  = (const float*)d_in[4];
  const float* b0  = (const float*)d_in[5];
  const float* Wl1 = (const float*)d_in[6];
  const float* Wr1 = (const float*)d_in[7];
  const float* a1  = (const float*)d_in[8];
  const float* b1  = (const float*)d_in[9];
  const float* Wl2 = (const float*)d_in[10];
  const float* Wr2 = (const float*)d_in[11];
  const float* a2  = (const float*)d_in[12];
  const float* b2  = (const float*)d_in[13];

  const int N = in_sizes[0] / NFEAT;   // 50000
  const int E = in_sizes[1] / 2;       // 800000
  const int* src = ei;
  const int* dst = ei + E;
  const int total = E + N;

  // workspace carve-up
  char* ws = (char*)d_ws;
  unsigned short* xlb = (unsigned short*)ws; ws += (size_t)N * HID * 2;
  unsigned short* xrb = (unsigned short*)ws; ws += (size_t)N * HID * 2;
  unsigned short* xb  = (unsigned short*)ws; ws += (size_t)N * HID * 2;
  unsigned short* hb  = (unsigned short*)ws; ws += (size_t)N * HID * 2;
  unsigned short* WT  = (unsigned short*)ws; ws += (size_t)6 * HID * HID * 2;
  float* logit8 = (float*)ws; ws += (size_t)total * 8 * sizeof(float);  // hc logits; l2 aliases first `total`
  float* att48 = (float*)ws; ws += 64 * sizeof(float);
  int* deg    = (int*)ws; ws += (size_t)N * sizeof(int);
  int* rowptr = (int*)ws; ws += (size_t)(N + 8) * sizeof(int);
  int* bsum   = (int*)ws; ws += (size_t)64 * sizeof(int);
  int2* csr   = (int2*)ws; ws += (size_t)total * sizeof(int2);

  unsigned short* WlT0 = WT + 0 * HID * HID;
  unsigned short* WrT0 = WT + 1 * HID * HID;
  unsigned short* WlT1 = WT + 2 * HID * HID;
  unsigned short* WrT1 = WT + 3 * HID * HID;
  unsigned short* WlT2 = WT + 4 * HID * HID;
  unsigned short* WrT2 = WT + 5 * HID * HID;

  const int TB = 256;
  const int nbScan = (N + 1023) / 1024;
  const int n4 = N * NFEAT / 4;

  // --- kernel 1: weight transposes + att pad + deg init ---
  {
    WtArgs a;
    const float* Wsrc[6] = {Wl0, Wr0, Wl1, Wr1, Wl2, Wr2};
    unsigned short* Wdst[6] = {WlT0, WrT0, WlT1, WrT1, WlT2, WrT2};
    int Ks[6] = {NFEAT, NFEAT, HID, HID, HID, HID};
    int Ms[6] = {HID, HID, HID, HID, NCLS, NCLS};
    int Mp[6] = {HID, HID, HID, HID, L2PAD, L2PAD};
    int off = 0;
    for (int s = 0; s < 6; ++s) {
      a.W[s] = Wsrc[s]; a.WT[s] = Wdst[s]; a.K[s] = Ks[s]; a.M[s] = Ms[s];
      a.off[s] = off; off += Mp[s] * Ks[s];
    }
    a.total = off;
    a.att = a2; a.att48 = att48;
    a.deg = deg; a.n = N;
    k_wt_all<<<(a.total + 48 + N + TB - 1) / TB, TB, 0, stream>>>(a);
  }
  // --- kernel 2: cast + degree count ---
  k_cast_count<<<(n4 + E + TB - 1) / TB, TB, 0, stream>>>(x, xb, n4, dst, deg, E);

  // --- CSR build ---
  k_bsum<<<nbScan, TB, 0, stream>>>(deg, bsum, N);
  k_scanb<<<1, 64, 0, stream>>>(bsum, nbScan);
  k_scanfinal<<<nbScan, TB, 0, stream>>>(deg, bsum, rowptr, csr, deg, N);
  k_scatter<<<(E + TB - 1) / TB, TB, 0, stream>>>(src, dst, deg, csr, E);

  const int nodeBlocks = (N + 3) / 4;
  const int rb128 = (N + 127) / 128;
  const int rb64 = (N + 63) / 64;
  const int l2Blocks = (N + 15) / 16;
  const int lgBlocks = ((total * 8) + TB - 1) / TB;

  // --- layer 0 ---
  {
    dim3 g(HID / 128, rb128);
    gemm_dual_bf16_128<<<g, 512, 0, stream>>>(xb, WlT0, WrT0, xlb, xrb, N, NFEAT, HID);
    k_logit_hc<<<lgBlocks, TB, 0, stream>>>(xlb, xrb, a0, csr, logit8, total);
    gat_node_hc<<<nodeBlocks, 256, 0, stream>>>(xlb, logit8, b0, rowptr, csr, hb, N);
  }
  // --- layer 1 ---
  {
    dim3 g(HID / 128, rb128);
    gemm_dual_bf16_128<<<g, 512, 0, stream>>>(hb, WlT1, WrT1, xlb, xrb, N, HID, HID);
    k_logit_hc<<<lgBlocks, TB, 0, stream>>>(xlb, xrb, a1, csr, logit8, total);
    gat_node_hc<<<nodeBlocks, 256, 0, stream>>>(xlb, logit8, b1, rowptr, csr, xb, N);
  }
  // --- layer 2 ---
  {
    dim3 g(1, rb64);
    gemm_dual_bf16<<<g, 256, 0, stream>>>(xb, WlT2, WrT2, xlb, xrb, N, HID, L2PAD);
    k_logit_l2<<<(total + TB - 1) / TB, TB, 0, stream>>>(xlb, xrb, att48, csr,
                                                         logit8, total);
    gat_node_l2<<<l2Blocks, 256, 0, stream>>>(xlb, logit8, b2, rowptr, csr,
                                              (float*)d_out, N);
  }
}

// Round 15
// 359.892 us; speedup vs baseline: 1.7932x; 1.7932x over previous
//
#include <hip/hip_runtime.h>
#include <cmath>

// GATv2 3-layer forward, round 14: exact revert to R13 (361.2 us best).
// R14's hc logit/agg split regressed 361->645 (k_logit_hc latency-bound at
// 19% VALUBusy; xr re-gathered per edge + xl read twice). Fused hc restored.

#define NFEAT 128
#define HID 256
#define NCLS 47
#define L2PAD 64
#define LOG2E 1.44269504088896340736f

typedef __attribute__((ext_vector_type(8))) short bf16x8;
typedef __attribute__((ext_vector_type(4))) float f32x4;
typedef __attribute__((ext_vector_type(2))) float f32x2;

__device__ __forceinline__ unsigned short f2b(float f) {
  unsigned int u = __builtin_bit_cast(unsigned int, f);
  u += 0x7FFFu + ((u >> 16) & 1u);  // RNE
  return (unsigned short)(u >> 16);
}
__device__ __forceinline__ float b2f(unsigned short s) {
  return __builtin_bit_cast(float, (unsigned int)s << 16);
}
__device__ __forceinline__ f32x2 b2f2(unsigned int u) {
  return (f32x2){__builtin_bit_cast(float, u << 16),
                 __builtin_bit_cast(float, u & 0xFFFF0000u)};
}
__device__ __forceinline__ void glds16(const unsigned short* g, unsigned short* l) {
  __builtin_amdgcn_global_load_lds(
      (const __attribute__((address_space(1))) unsigned int*)g,
      (__attribute__((address_space(3))) unsigned int*)l, 16, 0, 0);
}

// sum over 4-lane groups (quads) via DPP — pure VALU, no LDS
__device__ __forceinline__ float quad_sum(float v) {
  int t = __builtin_amdgcn_mov_dpp(__builtin_bit_cast(int, v), 0xB1, 0xF, 0xF, true);
  v += __builtin_bit_cast(float, t);  // quad_perm [1,0,3,2]
  t = __builtin_amdgcn_mov_dpp(__builtin_bit_cast(int, v), 0x4E, 0xF, 0xF, true);
  v += __builtin_bit_cast(float, t);  // quad_perm [2,3,0,1]
  return v;
}

// ---------------- kernel 1: weight transposes + att pad + deg init ----------------
struct WtArgs {
  const float* W[6];
  unsigned short* WT[6];
  int K[6], M[6], off[6], total;
  const float* att;
  float* att48;
  int* deg;        // init to 1 (self-loop)
  int n;
};
__global__ void k_wt_all(WtArgs a) {
  int i = blockIdx.x * blockDim.x + threadIdx.x;
  if (i >= a.total) {
    int j = i - a.total;
    if (j < 48) { a.att48[j] = (j < NCLS) ? a.att[j] * LOG2E : 0.f; return; }
    j -= 48;
    if (j < a.n) a.deg[j] = 1;
    return;
  }
  int s = 0;
  #pragma unroll
  for (int j = 1; j < 6; ++j) if (i >= a.off[j]) s = j;
  int jj = i - a.off[s];
  int K = a.K[s], M = a.M[s];
  int m = jj / K, k = jj - m * K;
  a.WT[s][jj] = (m < M) ? f2b(a.W[s][(size_t)k * M + m]) : (unsigned short)0;
}

// ---------------- kernel 2: cast x to bf16 + degree count ----------------
__global__ void k_cast_count(const float* __restrict__ in,
                             unsigned short* __restrict__ out, int n4,
                             const int* __restrict__ dst,
                             int* __restrict__ deg, int e) {
  int i = blockIdx.x * blockDim.x + threadIdx.x;
  if (i < n4) {
    float4 v = reinterpret_cast<const float4*>(in)[i];
    ushort4 o = {f2b(v.x), f2b(v.y), f2b(v.z), f2b(v.w)};
    reinterpret_cast<ushort4*>(out)[i] = o;
  } else {
    int j = i - n4;
    if (j < e) atomicAdd(&deg[dst[j]], 1);
  }
}

// ---------------- CSR build ----------------
__global__ __launch_bounds__(256) void k_bsum(const int* __restrict__ deg,
                                              int* __restrict__ bsum, int n) {
  int t = threadIdx.x;
  int base = blockIdx.x * 1024 + t * 4;
  int s = 0;
  if (base + 3 < n) {
    int4 v = *reinterpret_cast<const int4*>(deg + base);
    s = v.x + v.y + v.z + v.w;
  } else {
    for (int j = 0; j < 4; ++j) { int i = base + j; if (i < n) s += deg[i]; }
  }
  #pragma unroll
  for (int off = 1; off < 64; off <<= 1) s += __shfl_xor(s, off, 64);
  __shared__ int wsum[4];
  if ((t & 63) == 0) wsum[t >> 6] = s;
  __syncthreads();
  if (t == 0) bsum[blockIdx.x] = wsum[0] + wsum[1] + wsum[2] + wsum[3];
}

__global__ void k_scanb(int* __restrict__ bsum, int nb) {
  int lane = threadIdx.x;
  int v = (lane < nb) ? bsum[lane] : 0;
  #pragma unroll
  for (int off = 1; off < 64; off <<= 1) {
    int u = __shfl_up(v, off, 64);
    if (lane >= off) v += u;
  }
  if (lane < nb) bsum[lane] = v;
}

// scan-final + CSR self-loop init + cursor init (cursor aliases deg)
__global__ __launch_bounds__(256) void k_scanfinal(const int* __restrict__ deg,
                                                   const int* __restrict__ bscan,
                                                   int* __restrict__ rowptr,
                                                   int2* __restrict__ csr,
                                                   int* __restrict__ cursor, int n) {
  int t = threadIdx.x, b = blockIdx.x;
  int base = b * 1024 + t * 4;
  int v0 = 0, v1 = 0, v2 = 0, v3 = 0;
  if (base + 3 < n) {
    int4 v = *reinterpret_cast<const int4*>(deg + base);
    v0 = v.x; v1 = v.y; v2 = v.z; v3 = v.w;
  } else {
    if (base < n) v0 = deg[base];
    if (base + 1 < n) v1 = deg[base + 1];
    if (base + 2 < n) v2 = deg[base + 2];
    if (base + 3 < n) v3 = deg[base + 3];
  }
  int s = v0 + v1 + v2 + v3;
  int incl = s;
  #pragma unroll
  for (int off = 1; off < 64; off <<= 1) {
    int u = __shfl_up(incl, off, 64);
    if ((t & 63) >= off) incl += u;
  }
  __shared__ int wsum[4];
  int w = t >> 6, l = t & 63;
  if (l == 63) wsum[w] = incl;
  __syncthreads();
  int woff = 0;
  for (int j = 0; j < w; ++j) woff += wsum[j];
  int excl = incl - s + woff;
  int boff = (b == 0) ? 0 : bscan[b - 1];
  int p0 = boff + excl;
  int p1 = p0 + v0, p2 = p1 + v1, p3 = p2 + v2, p4 = p3 + v3;
  if (base < n)     { rowptr[base + 1] = p1; csr[p0] = make_int2(base, base);         cursor[base]     = p0 + 1; }
  if (base + 1 < n) { rowptr[base + 2] = p2; csr[p1] = make_int2(base + 1, base + 1); cursor[base + 1] = p1 + 1; }
  if (base + 2 < n) { rowptr[base + 3] = p3; csr[p2] = make_int2(base + 2, base + 2); cursor[base + 2] = p2 + 1; }
  if (base + 3 < n) { rowptr[base + 4] = p4; csr[p3] = make_int2(base + 3, base + 3); cursor[base + 3] = p3 + 1; }
  if (b == 0 && t == 0) rowptr[0] = 0;
}

__global__ void k_scatter(const int* __restrict__ src, const int* __restrict__ dst,
                          int* __restrict__ cursor, int2* __restrict__ csr, int e) {
  int i = blockIdx.x * blockDim.x + threadIdx.x;
  if (i < e) {
    int d = dst[i];
    int p = atomicAdd(&cursor[d], 1);
    csr[p] = make_int2(src[i], d);  // one 8B store
  }
}

// ---------------- 128x128 dual bf16 MFMA GEMM ----------------
__global__ __launch_bounds__(512) void gemm_dual_bf16_128(
    const unsigned short* __restrict__ X, const unsigned short* __restrict__ WlT,
    const unsigned short* __restrict__ WrT, unsigned short* __restrict__ XL,
    unsigned short* __restrict__ XR, int N, int K, int Mpad) {
  __shared__ __align__(16) unsigned short S[3 * 128 * 64];
  unsigned short* Xs = S;
  unsigned short* Ls = S + 8192;
  unsigned short* Rs = S + 16384;

  const int t = threadIdx.x;
  const int col0 = blockIdx.x * 128;
  const int row0 = blockIdx.y * 128;
  const int w = t >> 6, lane = t & 63;
  const int wr = w >> 2, wc = w & 3;
  const int r15 = lane & 15, kc = lane >> 4;
  const bool tail = (row0 + 128 > N);

  const int row_a = t >> 3,          c16_a = t & 7;
  const int row_b = (t + 512) >> 3,  c16_b = t & 7;
  const int sg_a = (c16_a ^ (row_a & 7)) * 8;
  const int sg_b = (c16_b ^ (row_b & 7)) * 8;
  unsigned short* d0 = S + w * 512;
  unsigned short* d1 = S + 4096 + w * 512;

  f32x4 accL[4][2], accR[4][2];
  #pragma unroll
  for (int rf = 0; rf < 4; ++rf)
    #pragma unroll
    for (int cf = 0; cf < 2; ++cf) {
      accL[rf][cf] = (f32x4){0.f, 0.f, 0.f, 0.f};
      accR[rf][cf] = (f32x4){0.f, 0.f, 0.f, 0.f};
    }

  for (int k0 = 0; k0 < K; k0 += 64) {
    glds16(WlT + (size_t)(col0 + row_a) * K + k0 + sg_a, d0 + 8192);
    glds16(WlT + (size_t)(col0 + row_b) * K + k0 + sg_b, d1 + 8192);
    glds16(WrT + (size_t)(col0 + row_a) * K + k0 + sg_a, d0 + 16384);
    glds16(WrT + (size_t)(col0 + row_b) * K + k0 + sg_b, d1 + 16384);
    if (!tail) {
      glds16(X + (size_t)(row0 + row_a) * K + k0 + sg_a, d0);
      glds16(X + (size_t)(row0 + row_b) * K + k0 + sg_b, d1);
    } else {
      uint4 va = (uint4){0, 0, 0, 0}, vb = (uint4){0, 0, 0, 0};
      if (row0 + row_a < N)
        va = *reinterpret_cast<const uint4*>(X + (size_t)(row0 + row_a) * K + k0 + sg_a);
      if (row0 + row_b < N)
        vb = *reinterpret_cast<const uint4*>(X + (size_t)(row0 + row_b) * K + k0 + sg_b);
      *reinterpret_cast<uint4*>(Xs + row_a * 64 + c16_a * 8) = va;
      *reinterpret_cast<uint4*>(Xs + row_b * 64 + c16_b * 8) = vb;
    }
    __syncthreads();

    #pragma unroll
    for (int ks = 0; ks < 2; ++ks) {
      const int c16 = ks * 4 + kc;
      bf16x8 a[4];
      #pragma unroll
      for (int rf = 0; rf < 4; ++rf) {
        const int rA = wr * 64 + rf * 16 + r15;
        a[rf] = *reinterpret_cast<const bf16x8*>(Xs + rA * 64 + ((c16 ^ (rA & 7)) * 8));
      }
      #pragma unroll
      for (int cf = 0; cf < 2; ++cf) {
        const int rB = wc * 32 + cf * 16 + r15;
        const int so = rB * 64 + ((c16 ^ (rB & 7)) * 8);
        const bf16x8 bl = *reinterpret_cast<const bf16x8*>(Ls + so);
        const bf16x8 br = *reinterpret_cast<const bf16x8*>(Rs + so);
        #pragma unroll
        for (int rf = 0; rf < 4; ++rf) {
          accL[rf][cf] = __builtin_amdgcn_mfma_f32_16x16x32_bf16(a[rf], bl, accL[rf][cf], 0, 0, 0);
          accR[rf][cf] = __builtin_amdgcn_mfma_f32_16x16x32_bf16(a[rf], br, accR[rf][cf], 0, 0, 0);
        }
      }
    }
    __syncthreads();
  }

  #pragma unroll
  for (int rf = 0; rf < 4; ++rf) {
    #pragma unroll
    for (int cf = 0; cf < 2; ++cf) {
      int cc = col0 + wc * 32 + cf * 16 + r15;
      #pragma unroll
      for (int i = 0; i < 4; ++i) {
        int rr = row0 + wr * 64 + rf * 16 + kc * 4 + i;
        if (rr < N) {
          XL[(size_t)rr * Mpad + cc] = f2b(accL[rf][cf][i]);
          XR[(size_t)rr * Mpad + cc] = f2b(accR[rf][cf][i]);
        }
      }
    }
  }
}

// ---------------- 64x64 dual GEMM (layer 2) ----------------
__global__ __launch_bounds__(256) void gemm_dual_bf16(
    const unsigned short* __restrict__ X, const unsigned short* __restrict__ WlT,
    const unsigned short* __restrict__ WrT, unsigned short* __restrict__ XL,
    unsigned short* __restrict__ XR, int N, int K, int Mpad) {
  __shared__ __align__(16) unsigned short S[3 * 64 * 64];
  unsigned short* Xs = S;
  unsigned short* Ls = S + 4096;
  unsigned short* Rs = S + 8192;

  const int t = threadIdx.x;
  const int col0 = blockIdx.x * 64;
  const int row0 = blockIdx.y * 64;
  const int w = t >> 6, lane = t & 63;
  const int r15 = lane & 15, kc = lane >> 4;
  const bool tail = (row0 + 64 > N);

  const int rowa = t >> 3, c16a = t & 7;
  const int rowb = (t + 256) >> 3, c16b = t & 7;
  const int sga = (c16a ^ (rowa & 7)) * 8;
  const int sgb = (c16b ^ (rowb & 7)) * 8;
  unsigned short* ldst0 = S + (w * 512);
  unsigned short* ldst1 = S + (2048 + w * 512);

  f32x4 accL[4], accR[4];
  #pragma unroll
  for (int i = 0; i < 4; ++i) {
    accL[i] = (f32x4){0.f, 0.f, 0.f, 0.f};
    accR[i] = (f32x4){0.f, 0.f, 0.f, 0.f};
  }

  const int rA = 16 * w + r15;

  for (int k0 = 0; k0 < K; k0 += 64) {
    glds16(WlT + (size_t)(col0 + rowa) * K + k0 + sga, ldst0 + 4096);
    glds16(WlT + (size_t)(col0 + rowb) * K + k0 + sgb, ldst1 + 4096);
    glds16(WrT + (size_t)(col0 + rowa) * K + k0 + sga, ldst0 + 8192);
    glds16(WrT + (size_t)(col0 + rowb) * K + k0 + sgb, ldst1 + 8192);
    if (!tail) {
      glds16(X + (size_t)(row0 + rowa) * K + k0 + sga, ldst0);
      glds16(X + (size_t)(row0 + rowb) * K + k0 + sgb, ldst1);
    } else {
      uint4 va = (uint4){0, 0, 0, 0}, vb = (uint4){0, 0, 0, 0};
      if (row0 + rowa < N)
        va = *reinterpret_cast<const uint4*>(X + (size_t)(row0 + rowa) * K + k0 + sga);
      if (row0 + rowb < N)
        vb = *reinterpret_cast<const uint4*>(X + (size_t)(row0 + rowb) * K + k0 + sgb);
      *reinterpret_cast<uint4*>(Xs + rowa * 64 + c16a * 8) = va;
      *reinterpret_cast<uint4*>(Xs + rowb * 64 + c16b * 8) = vb;
    }
    __syncthreads();

    #pragma unroll
    for (int ks = 0; ks < 2; ++ks) {
      const int c16 = ks * 4 + kc;
      const bf16x8 a = *reinterpret_cast<const bf16x8*>(
          Xs + rA * 64 + ((c16 ^ (rA & 7)) * 8));
      #pragma unroll
      for (int nf = 0; nf < 4; ++nf) {
        const int rB = nf * 16 + r15;
        const int so = rB * 64 + ((c16 ^ (rB & 7)) * 8);
        const bf16x8 bl = *reinterpret_cast<const bf16x8*>(Ls + so);
        const bf16x8 br = *reinterpret_cast<const bf16x8*>(Rs + so);
        accL[nf] = __builtin_amdgcn_mfma_f32_16x16x32_bf16(a, bl, accL[nf], 0, 0, 0);
        accR[nf] = __builtin_amdgcn_mfma_f32_16x16x32_bf16(a, br, accR[nf], 0, 0, 0);
      }
    }
    __syncthreads();
  }

  #pragma unroll
  for (int nf = 0; nf < 4; ++nf) {
    int cc = col0 + nf * 16 + r15;
    #pragma unroll
    for (int i = 0; i < 4; ++i) {
      int rr = row0 + 16 * w + kc * 4 + i;
      if (rr < N) {
        XL[(size_t)rr * Mpad + cc] = f2b(accL[nf][i]);
        XR[(size_t)rr * Mpad + cc] = f2b(accR[nf][i]);
      }
    }
  }
}

// ---------------- fused node kernel, layers 0/1 (H=8, C=32) ----------------
// 1 wave/node; half-wave per edge, 2 edges/iter; slot q holds values
// [8q,8q+8); head = q>>2; reduce via DPP quad_perm (no LDS).
__global__ __launch_bounds__(256) void gat_node_hc(
    const unsigned short* __restrict__ xl, const unsigned short* __restrict__ xr,
    const float* __restrict__ att, const float* __restrict__ bias,
    const int* __restrict__ rowptr, const int2* __restrict__ csr,
    unsigned short* __restrict__ out, int n) {
  int wid = (blockIdx.x * blockDim.x + threadIdx.x) >> 6;
  int lane = threadIdx.x & 63;
  if (wid >= n) return;
  const int q = lane & 31, half = lane >> 5;

  const uint4 xrp = *reinterpret_cast<const uint4*>(xr + (size_t)wid * HID + q * 8);
  const f32x2 xr2[4] = {b2f2(xrp.x), b2f2(xrp.y), b2f2(xrp.z), b2f2(xrp.w)};
  const float4 af0 = *reinterpret_cast<const float4*>(att + q * 8);
  const float4 af1 = *reinterpret_cast<const float4*>(att + q * 8 + 4);
  const f32x2 a2[4] = {{af0.x, af0.y}, {af0.z, af0.w},
                       {af1.x, af1.y}, {af1.z, af1.w}};

  float m = -1e30f, denom = 0.f;
  f32x2 acc[4] = {{0.f, 0.f}, {0.f, 0.f}, {0.f, 0.f}, {0.f, 0.f}};

  const int beg = rowptr[wid], end = rowptr[wid + 1];
  const int* csr_src = reinterpret_cast<const int*>(csr);  // stride-2 src view
  for (int base = beg; base < end; base += 2) {
    const int i = base + half;
    const bool act = i < end;
    const int u = csr_src[2 * (act ? i : base)];
    const uint4 p = *reinterpret_cast<const uint4*>(xl + (size_t)u * HID + q * 8);
    const f32x2 x2[4] = {b2f2(p.x), b2f2(p.y), b2f2(p.z), b2f2(p.w)};
    f32x2 s2 = {0.f, 0.f};
    #pragma unroll
    for (int j = 0; j < 4; ++j) {
      f32x2 z = x2[j] + xr2[j];
      f32x2 lz = 0.2f * z;
      f32x2 r = {fmaxf(z.x, lz.x), fmaxf(z.y, lz.y)};
      s2 += r * a2[j];
    }
    float part = quad_sum(s2.x + s2.y);  // per-head logit, head = q>>2
    if (!act) part = -1e30f;
    if (__any(part > m + 8.f)) {
      float mn = fmaxf(m, part);
      float so = __expf(m - mn);
      float wn = act ? __expf(part - mn) : 0.f;
      denom = denom * so + wn;
      #pragma unroll
      for (int j = 0; j < 4; ++j) acc[j] = acc[j] * so + wn * x2[j];
      m = mn;
    } else {
      float wn = act ? __expf(part - m) : 0.f;
      denom += wn;
      #pragma unroll
      for (int j = 0; j < 4; ++j) acc[j] += wn * x2[j];
    }
  }

  // merge the two half-wave softmax states
  float mo = __shfl_xor(m, 32, 64);
  float ms = fmaxf(m, mo);
  float sc = __expf(m - ms);
  denom *= sc;
  denom += __shfl_xor(denom, 32, 64);
  #pragma unroll
  for (int j = 0; j < 4; ++j) {
    acc[j] *= sc;
    acc[j].x += __shfl_xor(acc[j].x, 32, 64);
    acc[j].y += __shfl_xor(acc[j].y, 32, 64);
  }

  if (half == 0) {
    const float inv = 1.f / (denom + 1e-16f);
    const float4 bf0 = *reinterpret_cast<const float4*>(bias + q * 8);
    const float4 bf1 = *reinterpret_cast<const float4*>(bias + q * 8 + 4);
    float o[8] = {acc[0].x * inv + bf0.x, acc[0].y * inv + bf0.y,
                  acc[1].x * inv + bf0.z, acc[1].y * inv + bf0.w,
                  acc[2].x * inv + bf1.x, acc[2].y * inv + bf1.y,
                  acc[3].x * inv + bf1.z, acc[3].y * inv + bf1.w};
    #pragma unroll
    for (int j = 0; j < 8; ++j) o[j] = o[j] > 0.f ? o[j] : (__expf(o[j]) - 1.f);
    uint4 ov;
    ov.x = (unsigned)f2b(o[0]) | ((unsigned)f2b(o[1]) << 16);
    ov.y = (unsigned)f2b(o[2]) | ((unsigned)f2b(o[3]) << 16);
    ov.z = (unsigned)f2b(o[4]) | ((unsigned)f2b(o[5]) << 16);
    ov.w = (unsigned)f2b(o[6]) | ((unsigned)f2b(o[7]) << 16);
    *reinterpret_cast<uint4*>(out + (size_t)wid * HID + q * 8) = ov;
  }
}

// ---------------- layer-2 edge logits (lane = CSR slot) ----------------
__global__ __launch_bounds__(256) void k_logit_l2(
    const unsigned short* __restrict__ xl, const unsigned short* __restrict__ xr,
    const float* __restrict__ att48, const int2* __restrict__ csr,
    float* __restrict__ logit, int total) {
  int i = blockIdx.x * blockDim.x + threadIdx.x;
  if (i >= total) return;
  const int2 e = csr[i];
  const uint4* pu = reinterpret_cast<const uint4*>(xl + (size_t)e.x * L2PAD);
  const uint4* pv = reinterpret_cast<const uint4*>(xr + (size_t)e.y * L2PAD);
  f32x2 s2 = {0.f, 0.f};
  #pragma unroll
  for (int b = 0; b < 6; ++b) {
    const uint4 xu = pu[b], xv = pv[b];
    const f32x2* a2 = reinterpret_cast<const f32x2*>(att48 + b * 8);
    const unsigned ua[4] = {xu.x, xu.y, xu.z, xu.w};
    const unsigned va[4] = {xv.x, xv.y, xv.z, xv.w};
    #pragma unroll
    for (int j = 0; j < 4; ++j) {
      f32x2 z = b2f2(ua[j]) + b2f2(va[j]);
      f32x2 lz = 0.2f * z;
      f32x2 r = {fmaxf(z.x, lz.x), fmaxf(z.y, lz.y)};
      s2 += r * a2[j];
    }
  }
  logit[i] = s2.x + s2.y;  // log2 units (att48 pre-scaled)
}

// ---------------- layer-2 aggregation + log_softmax ----------------
// QUARTER-WAVE per node: lane q in [0,16) holds classes {4q..4q+3} (uint2 =
// 4xbf16 loads); reductions within the 16-lane group (4 stages).
__global__ __launch_bounds__(256) void gat_node_l2(
    const unsigned short* __restrict__ xl, const float* __restrict__ logit,
    const float* __restrict__ bias, const int* __restrict__ rowptr,
    const int2* __restrict__ csr, float* __restrict__ out, int n) {
  int tid = blockIdx.x * blockDim.x + threadIdx.x;
  int node = tid >> 4;
  int q = threadIdx.x & 15;
  if (node >= n) return;
  const int c0 = 4 * q;
  const bool g0 = c0 < NCLS;          // lane has at least one valid class
  const bool a1 = (c0 + 1) < NCLS, a2c = (c0 + 2) < NCLS, a3 = (c0 + 3) < NCLS;
  const int beg = rowptr[node], end = rowptr[node + 1];
  const int* csr_src = reinterpret_cast<const int*>(csr);

  // node max over logits (within the 16-lane group)
  float mx = -1e30f;
  for (int i = beg + q; i < end; i += 16) mx = fmaxf(mx, logit[i]);
  #pragma unroll
  for (int off = 1; off < 16; off <<= 1) mx = fmaxf(mx, __shfl_xor(mx, off, 64));

  float denom = 0.f;      // group-uniform
  f32x2 acc0 = {0.f, 0.f}, acc1 = {0.f, 0.f};
  int i = beg;
  for (; i + 1 < end; i += 2) {
    const int u0 = csr_src[2 * i], u1 = csr_src[2 * (i + 1)];
    uint2 p0 = {0u, 0u}, p1 = {0u, 0u};
    if (g0) {
      p0 = *reinterpret_cast<const uint2*>(xl + (size_t)u0 * L2PAD + c0);
      p1 = *reinterpret_cast<const uint2*>(xl + (size_t)u1 * L2PAD + c0);
    }
    const float w0 = exp2f(logit[i] - mx);
    const float w1 = exp2f(logit[i + 1] - mx);
    denom += w0 + w1;
    acc0 += w0 * b2f2(p0.x) + w1 * b2f2(p1.x);
    acc1 += w0 * b2f2(p0.y) + w1 * b2f2(p1.y);
  }
  if (i < end) {
    const int u0 = csr_src[2 * i];
    uint2 p0 = {0u, 0u};
    if (g0) p0 = *reinterpret_cast<const uint2*>(xl + (size_t)u0 * L2PAD + c0);
    const float w0 = exp2f(logit[i] - mx);
    denom += w0;
    acc0 += w0 * b2f2(p0.x);
    acc1 += w0 * b2f2(p0.y);
  }

  const float inv = 1.f / (denom + 1e-16f);
  f32x2 r0 = acc0 * inv, r1 = acc1 * inv;
  if (g0)  r0.x += bias[c0];
  if (a1)  r0.y += bias[c0 + 1];
  if (a2c) r1.x += bias[c0 + 2];
  if (a3)  r1.y += bias[c0 + 3];

  // log_softmax over 47 classes held 4-per-lane across the 16-lane group
  float rm = -1e30f;
  if (g0)  rm = fmaxf(rm, r0.x);
  if (a1)  rm = fmaxf(rm, r0.y);
  if (a2c) rm = fmaxf(rm, r1.x);
  if (a3)  rm = fmaxf(rm, r1.y);
  #pragma unroll
  for (int off = 1; off < 16; off <<= 1) rm = fmaxf(rm, __shfl_xor(rm, off, 64));
  float se = 0.f;
  if (g0)  se += __expf(r0.x - rm);
  if (a1)  se += __expf(r0.y - rm);
  if (a2c) se += __expf(r1.x - rm);
  if (a3)  se += __expf(r1.y - rm);
  #pragma unroll
  for (int off = 1; off < 16; off <<= 1) se += __shfl_xor(se, off, 64);
  const float ls = rm + __logf(se);
  float* o = out + (size_t)node * NCLS;
  if (g0)  o[c0] = r0.x - ls;
  if (a1)  o[c0 + 1] = r0.y - ls;
  if (a2c) o[c0 + 2] = r1.x - ls;
  if (a3)  o[c0 + 3] = r1.y - ls;
}

// ---------------- launch ----------------
extern "C" void kernel_launch(void* const* d_in, const int* in_sizes, int n_in,
                              void* d_out, int out_size, void* d_ws, size_t ws_size,
                              hipStream_t stream) {
  const float* x   = (const float*)d_in[0];
  const int* ei    = (const int*)d_in[1];
  const float* Wl0 = (const float*)d_in[2];
  const float* Wr0 = (const float*)d_in[3];
  const float* a0  = (const float*)d_in[4];
  const float* b0  = (const float*)d_in[5];
  const float* Wl1 = (const float*)d_in[6];
  const float* Wr1 = (const float*)d_in[7];
  const float* a1  = (const float*)d_in[8];
  const float* b1  = (const float*)d_in[9];
  const float* Wl2 = (const float*)d_in[10];
  const float* Wr2 = (const float*)d_in[11];
  const float* a2  = (const float*)d_in[12];
  const float* b2  = (const float*)d_in[13];

  const int N = in_sizes[0] / NFEAT;   // 50000
  const int E = in_sizes[1] / 2;       // 800000
  const int* src = ei;
  const int* dst = ei + E;
  const int total = E + N;

  // workspace carve-up
  char* ws = (char*)d_ws;
  unsigned short* xlb = (unsigned short*)ws; ws += (size_t)N * HID * 2;
  unsigned short* xrb = (unsigned short*)ws; ws += (size_t)N * HID * 2;
  unsigned short* xb  = (unsigned short*)ws; ws += (size_t)N * HID * 2;
  unsigned short* hb  = (unsigned short*)ws; ws += (size_t)N * HID * 2;
  unsigned short* WT  = (unsigned short*)ws; ws += (size_t)6 * HID * HID * 2;
  float* logit = (float*)ws; ws += (size_t)total * sizeof(float);
  float* att48 = (float*)ws; ws += 64 * sizeof(float);
  int* deg    = (int*)ws; ws += (size_t)N * sizeof(int);
  int* rowptr = (int*)ws; ws += (size_t)(N + 8) * sizeof(int);
  int* bsum   = (int*)ws; ws += (size_t)64 * sizeof(int);
  int2* csr   = (int2*)ws; ws += (size_t)total * sizeof(int2);

  unsigned short* WlT0 = WT + 0 * HID * HID;
  unsigned short* WrT0 = WT + 1 * HID * HID;
  unsigned short* WlT1 = WT + 2 * HID * HID;
  unsigned short* WrT1 = WT + 3 * HID * HID;
  unsigned short* WlT2 = WT + 4 * HID * HID;
  unsigned short* WrT2 = WT + 5 * HID * HID;

  const int TB = 256;
  const int nbScan = (N + 1023) / 1024;
  const int n4 = N * NFEAT / 4;

  // --- kernel 1: weight transposes + att pad + deg init ---
  {
    WtArgs a;
    const float* Wsrc[6] = {Wl0, Wr0, Wl1, Wr1, Wl2, Wr2};
    unsigned short* Wdst[6] = {WlT0, WrT0, WlT1, WrT1, WlT2, WrT2};
    int Ks[6] = {NFEAT, NFEAT, HID, HID, HID, HID};
    int Ms[6] = {HID, HID, HID, HID, NCLS, NCLS};
    int Mp[6] = {HID, HID, HID, HID, L2PAD, L2PAD};
    int off = 0;
    for (int s = 0; s < 6; ++s) {
      a.W[s] = Wsrc[s]; a.WT[s] = Wdst[s]; a.K[s] = Ks[s]; a.M[s] = Ms[s];
      a.off[s] = off; off += Mp[s] * Ks[s];
    }
    a.total = off;
    a.att = a2; a.att48 = att48;
    a.deg = deg; a.n = N;
    k_wt_all<<<(a.total + 48 + N + TB - 1) / TB, TB, 0, stream>>>(a);
  }
  // --- kernel 2: cast + degree count (deg init done in kernel 1) ---
  k_cast_count<<<(n4 + E + TB - 1) / TB, TB, 0, stream>>>(x, xb, n4, dst, deg, E);

  // --- CSR build ---
  k_bsum<<<nbScan, TB, 0, stream>>>(deg, bsum, N);
  k_scanb<<<1, 64, 0, stream>>>(bsum, nbScan);
  k_scanfinal<<<nbScan, TB, 0, stream>>>(deg, bsum, rowptr, csr, deg, N);
  k_scatter<<<(E + TB - 1) / TB, TB, 0, stream>>>(src, dst, deg, csr, E);

  const int nodeBlocks = (N + 3) / 4;
  const int rb128 = (N + 127) / 128;
  const int rb64 = (N + 63) / 64;
  const int l2Blocks = (N + 15) / 16;  // quarter-wave per node, 16 nodes / block

  // --- layer 0 ---
  {
    dim3 g(HID / 128, rb128);
    gemm_dual_bf16_128<<<g, 512, 0, stream>>>(xb, WlT0, WrT0, xlb, xrb, N, NFEAT, HID);
    gat_node_hc<<<nodeBlocks, 256, 0, stream>>>(xlb, xrb, a0, b0, rowptr, csr, hb, N);
  }
  // --- layer 1 ---
  {
    dim3 g(HID / 128, rb128);
    gemm_dual_bf16_128<<<g, 512, 0, stream>>>(hb, WlT1, WrT1, xlb, xrb, N, HID, HID);
    gat_node_hc<<<nodeBlocks, 256, 0, stream>>>(xlb, xrb, a1, b1, rowptr, csr, xb, N);
  }
  // --- layer 2 ---
  {
    dim3 g(1, rb64);
    gemm_dual_bf16<<<g, 256, 0, stream>>>(xb, WlT2, WrT2, xlb, xrb, N, HID, L2PAD);
    k_logit_l2<<<(total + TB - 1) / TB, TB, 0, stream>>>(xlb, xrb, att48, csr,
                                                         logit, total);
    gat_node_l2<<<l2Blocks, 256, 0, stream>>>(xlb, logit, b2, rowptr, csr,
                                              (float*)d_out, N);
  }
}